// Round 6
// baseline (400.405 us; speedup 1.0000x reference)
//
#include <hip/hip_runtime.h>
#include <hip/hip_bf16.h>
#include <cstdint>

#define BN_SCALEF 0.99999500003749975f  // 1/sqrt(1+1e-5)
#define EXP_SHIFT 4.0f

// Problem constants: B=128, N=200, F=768, H=8, Fo=32, Fh=256

typedef _Float16 half8 __attribute__((ext_vector_type(8)));
typedef _Float16 half4 __attribute__((ext_vector_type(4)));
typedef float floatx4 __attribute__((ext_vector_type(4)));
typedef float floatx16 __attribute__((ext_vector_type(16)));

// ---------------------------------------------------------------- prep: pack_mask + Wcat^T + W2t  (one launch)

__global__ __launch_bounds__(256) void prep(const int* __restrict__ adj,
                                            const float* __restrict__ W_heads,
                                            const float* __restrict__ Ws_in,
                                            const float* __restrict__ Wp_in,
                                            const float* __restrict__ Wq_in,
                                            unsigned int* __restrict__ maskw,
                                            _Float16* __restrict__ Bt,
                                            float* __restrict__ W2t) {
    int blk = blockIdx.x;
    int t = threadIdx.x;
    if (blk < 1600) {
        int w = t >> 6, lane = t & 63;
        for (int task = w; task < 64; task += 4) {
            int r = blk * 16 + (task >> 2);
            int c0 = (task & 3) * 64;
            int j = c0 + lane;
            bool v = (j < 200) && (adj[(size_t)r * 200 + j] > 0);
            unsigned long long m = __ballot(v ? 1 : 0);
            if (lane == 0) {
                maskw[r * 8 + (c0 >> 5)]     = (unsigned int)(m & 0xffffffffULL);
                maskw[r * 8 + (c0 >> 5) + 1] = (unsigned int)(m >> 32);
            }
        }
    } else if (blk < 1792) {
        __shared__ float ld[32][36];
        int blk2 = blk - 1600;          // h = blk2/24, f-tile = blk2%24
        int h = blk2 / 24, f0 = (blk2 % 24) * 32;
        int idx = t * 4;
        int fr = idx >> 5, o0 = idx & 31;
        float4 v = *(const float4*)&W_heads[(size_t)h * 24576 + (size_t)(f0 + fr) * 32 + o0];
        ld[fr][o0] = v.x; ld[fr][o0 + 1] = v.y; ld[fr][o0 + 2] = v.z; ld[fr][o0 + 3] = v.w;
        __syncthreads();
        int o = idx >> 5, fr0 = idx & 31;
        half4 hv;
#pragma unroll
        for (int u = 0; u < 4; ++u) hv[u] = (_Float16)ld[fr0 + u][o];
        *(half4*)&Bt[(size_t)(h * 32 + o) * 768 + f0 + fr0] = hv;
    } else {
        for (int c = 0; c < 36; ++c) {
            float v;
            if (c < 2)      v = Ws_in[t * 2 + c];
            else if (c < 4) v = Wp_in[t * 2 + (c - 2)];
            else            v = Wq_in[t * 32 + (c - 4)];
            W2t[c * 256 + t] = v;
        }
    }
}

// ---------------------------------------------------------------- GEMM1: LDS-staged, 32x32x16 MFMA
// h16[25600,256] = A[25600,768] fp32 @ Bt^T (f16 [256][768])
// block = 32 rows x 256 cols, 256 thr = 4 waves; wave w = cols w*64 (2 tiles of 32)
// BK=32, register dist-1 prefetch, coalesced staging.

__global__ __launch_bounds__(256) void gemm1_mfma32(const float* __restrict__ A,
                                                    const _Float16* __restrict__ Bt,
                                                    _Float16* __restrict__ h16) {
    __shared__ __align__(16) _Float16 As[32 * 40];    // [row][k], pad 8
    __shared__ __align__(16) _Float16 Bs[256 * 40];   // [col][k], pad 8
    int t = threadIdx.x;
    int m0 = blockIdx.x * 32;       // 800 blocks
    int w = t >> 6, lane = t & 63;
    int l32 = lane & 31, half = lane >> 5;
    int c0 = w * 64;

    floatx16 acc[2];
#pragma unroll
    for (int i = 0; i < 16; ++i) { acc[0][i] = 0.f; acc[1][i] = 0.f; }

    int arow = t >> 3, akoff = (t & 7) * 4;    // A: 32 rows x 32 k, float4/thread
    int bcol = t >> 2, bkoff = (t & 3) * 8;    // B: 4 passes of 64 cols, 16B/thread
    const float*    Aptr = &A[(size_t)(m0 + arow) * 768 + akoff];
    const _Float16* Bptr = &Bt[(size_t)bcol * 768 + bkoff];

    float4 pa = *(const float4*)Aptr;
    uint4 pb[4];
#pragma unroll
    for (int p = 0; p < 4; ++p)
        pb[p] = *(const uint4*)(Bptr + (size_t)p * 64 * 768);

    for (int k0 = 0; k0 < 768; k0 += 32) {
        half4 ah;
        ah[0] = (_Float16)pa.x; ah[1] = (_Float16)pa.y;
        ah[2] = (_Float16)pa.z; ah[3] = (_Float16)pa.w;
        *(half4*)&As[arow * 40 + akoff] = ah;
#pragma unroll
        for (int p = 0; p < 4; ++p)
            *(uint4*)&Bs[(p * 64 + bcol) * 40 + bkoff] = pb[p];
        __syncthreads();
        if (k0 + 32 < 768) {
            pa = *(const float4*)(Aptr + k0 + 32);
#pragma unroll
            for (int p = 0; p < 4; ++p)
                pb[p] = *(const uint4*)(Bptr + (size_t)p * 64 * 768 + k0 + 32);
        }
        half8 af[2], bf[2][2];
#pragma unroll
        for (int kh = 0; kh < 2; ++kh) {
            af[kh] = *(half8*)&As[l32 * 40 + kh * 16 + half * 8];
#pragma unroll
            for (int ct = 0; ct < 2; ++ct)
                bf[ct][kh] = *(half8*)&Bs[(c0 + ct * 32 + l32) * 40 + kh * 16 + half * 8];
        }
#pragma unroll
        for (int kh = 0; kh < 2; ++kh) {
            acc[0] = __builtin_amdgcn_mfma_f32_32x32x16_f16(af[kh], bf[0][kh], acc[0], 0, 0, 0);
            acc[1] = __builtin_amdgcn_mfma_f32_32x32x16_f16(af[kh], bf[1][kh], acc[1], 0, 0, 0);
        }
        __syncthreads();
    }

    // C/D 32x32 layout: col = lane&31, row = (reg&3) + 8*(reg>>2) + 4*(lane>>5)
#pragma unroll
    for (int ct = 0; ct < 2; ++ct) {
        int gc = c0 + ct * 32 + l32;
#pragma unroll
        for (int reg = 0; reg < 16; ++reg) {
            int gr = m0 + (reg & 3) + 8 * (reg >> 2) + 4 * half;
            h16[(size_t)gr * 256 + gc] = (_Float16)acc[ct][reg];
        }
    }
}

// ---------------------------------------------------------------- head attention via MFMA (h16 in, x16 out)
// s1/s2 computed in-block from the LDS h-tile; mask words hoisted per tile.

__global__ __launch_bounds__(256) void attn_heads_mfma(
    const _Float16* __restrict__ h16,
    const float* __restrict__ a_h,
    const unsigned int* __restrict__ maskw,
    const float* __restrict__ bnh_g, const float* __restrict__ bnh_b,
    const float* __restrict__ bnt_g, const float* __restrict__ bnt_b,
    _Float16* __restrict__ x16) {
    __shared__ __align__(16) _Float16 Bs[48 * 228];   // [n][k]: n<32 h^T, n=32 ones, rest 0
    __shared__ __align__(16) _Float16 Ps[64 * 228];   // 4 waves x 16-row slabs
    __shared__ float s1s[256], s2s[256];
    int hb = blockIdx.x;
    int h = hb >> 7, b = hb & 127;
    int t = threadIdx.x;

    unsigned long long* bz = (unsigned long long*)Bs;
    for (int idx = t; idx < (48 * 228) / 4; idx += 256) bz[idx] = 0ULL;
    __syncthreads();
    for (int idx = t; idx < 800; idx += 256) {
        int j = idx >> 2, w8 = (idx & 3) * 8;
        half8 v = *(const half8*)&h16[(size_t)(b * 200 + j) * 256 + h * 32 + w8];
#pragma unroll
        for (int u = 0; u < 8; ++u) Bs[(w8 + u) * 228 + j] = v[u];
    }
    if (t < 200) Bs[32 * 228 + t] = (_Float16)1.0f;
    __syncthreads();

    // s1/s2 from the LDS h-tile (f16 h, fp32 accumulate)
    if (t < 200) {
        float acc1 = 0.f, acc2 = 0.f;
        const float* ab = &a_h[h * 64];
#pragma unroll
        for (int o = 0; o < 32; ++o) {
            float hv = (float)Bs[o * 228 + t];
            acc1 += hv * ab[o];
            acc2 += hv * ab[32 + o];
        }
        s1s[t] = acc1; s2s[t] = acc2;
    } else {
        s1s[t] = 0.f; s2s[t] = 0.f;
    }
    __syncthreads();

    int w = t >> 6, lane = t & 63;
    int l16 = lane & 15, quad = lane >> 4;
    _Float16* Pw = &Ps[w * 16 * 228];

    int j0 = lane * 4;
    float4 s2r = *(const float4*)&s2s[j0];

    for (int tile = w; tile < 13; tile += 4) {
        int i_base = tile * 16;
        int nrows = (i_base + 16 <= 200) ? 16 : (200 - i_base);
        // hoisted mask loads for the tile (vmcnt-pipelined batch)
        unsigned int mwr[16];
        for (int r16 = 0; r16 < nrows; ++r16)
            mwr[r16] = maskw[(size_t)(b * 200 + i_base + r16) * 8 + (lane >> 3)];
        for (int r16 = 0; r16 < nrows; ++r16) {
            int i = i_base + r16;
            float s1v = s1s[i];
            unsigned int mw = mwr[r16];
            half4 pv;
#pragma unroll
            for (int q = 0; q < 4; ++q) {
                float e = s1v + ((const float*)&s2r)[q];
                e = fmaxf(e, 0.3f * e);
                float p = ((mw >> ((j0 + q) & 31)) & 1u) ? __expf(e - EXP_SHIFT) : 0.f;
                pv[q] = (_Float16)p;
            }
            if (j0 < 228) *(half4*)&Pw[r16 * 228 + j0] = pv;
        }
        floatx4 acc0 = {0.f, 0.f, 0.f, 0.f};
        floatx4 acc1 = {0.f, 0.f, 0.f, 0.f};
        floatx4 acc2 = {0.f, 0.f, 0.f, 0.f};
#pragma unroll
        for (int kt = 0; kt < 7; ++kt) {
            half8 af = *(half8*)&Pw[l16 * 228 + kt * 32 + quad * 8];
            half8 b0 = *(half8*)&Bs[(l16) * 228 + kt * 32 + quad * 8];
            half8 b1 = *(half8*)&Bs[(16 + l16) * 228 + kt * 32 + quad * 8];
            half8 b2 = *(half8*)&Bs[(32 + l16) * 228 + kt * 32 + quad * 8];
            acc0 = __builtin_amdgcn_mfma_f32_16x16x32_f16(af, b0, acc0, 0, 0, 0);
            acc1 = __builtin_amdgcn_mfma_f32_16x16x32_f16(af, b1, acc1, 0, 0, 0);
            acc2 = __builtin_amdgcn_mfma_f32_16x16x32_f16(af, b2, acc2, 0, 0, 0);
        }
#pragma unroll
        for (int r = 0; r < 4; ++r) {
            int i = i_base + quad * 4 + r;
            float rsum = __shfl(acc2[r], (lane & 48), 64);
            if (i < 200) {
                float inv = 1.f / rsum;
                float g1 = BN_SCALEF * bnh_g[h * 200 + i], c1 = bnh_b[h * 200 + i];
                float g2 = BN_SCALEF * bnt_g[i], c2 = bnt_b[i];
                float v0 = acc0[r] * inv * g1 + c1;
                v0 = v0 > 0.f ? v0 : __expf(v0) - 1.f;
                v0 = v0 * g2 + c2;
                float v1 = acc1[r] * inv * g1 + c1;
                v1 = v1 > 0.f ? v1 : __expf(v1) - 1.f;
                v1 = v1 * g2 + c2;
                size_t base = (size_t)(b * 200 + i) * 256 + h * 32;
                x16[base + l16]      = (_Float16)v0;
                x16[base + 16 + l16] = (_Float16)v1;
            }
        }
    }
}

// ---------------------------------------------------------------- GEMM2 (x16 f16 in) + fused s12_second

__global__ __launch_bounds__(256) void gemm2s(const _Float16* __restrict__ X,
                                              const float* __restrict__ W2t,
                                              const float* __restrict__ a_sent,
                                              const float* __restrict__ a_para,
                                              const float* __restrict__ a_q,
                                              float* __restrict__ H2,
                                              float* __restrict__ sv) {
    __shared__ __align__(16) float Ws[36 * 260];
    __shared__ float Hs[128][37];
    int t = threadIdx.x;
#pragma unroll
    for (int rep = 0; rep < 9; ++rep) {
        int fidx = rep * 1024 + t * 4;
        int c = fidx >> 8, k = fidx & 255;
        *(float4*)&Ws[c * 260 + k] = *(const float4*)&W2t[fidx];
    }
    __syncthreads();
    int cg = t & 3, rt = t >> 2;
    int row0 = blockIdx.x * 128 + rt * 2;
    float acc[2][9] = {};
    for (int k = 0; k < 256; k += 8) {
        half8 x0 = *(const half8*)&X[(size_t)row0 * 256 + k];
        half8 x1 = *(const half8*)&X[(size_t)(row0 + 1) * 256 + k];
        float xf0[8], xf1[8];
#pragma unroll
        for (int u = 0; u < 8; ++u) { xf0[u] = (float)x0[u]; xf1[u] = (float)x1[u]; }
#pragma unroll
        for (int c = 0; c < 9; ++c) {
            const float* wr = &Ws[(cg * 9 + c) * 260 + k];
            float4 wa = *(float4*)wr;
            float4 wb = *(float4*)(wr + 4);
            acc[0][c] += xf0[0] * wa.x + xf0[1] * wa.y + xf0[2] * wa.z + xf0[3] * wa.w
                       + xf0[4] * wb.x + xf0[5] * wb.y + xf0[6] * wb.z + xf0[7] * wb.w;
            acc[1][c] += xf1[0] * wa.x + xf1[1] * wa.y + xf1[2] * wa.z + xf1[3] * wa.w
                       + xf1[4] * wb.x + xf1[5] * wb.y + xf1[6] * wb.z + xf1[7] * wb.w;
        }
    }
#pragma unroll
    for (int rr = 0; rr < 2; ++rr)
#pragma unroll
        for (int c = 0; c < 9; ++c) {
            H2[(size_t)(row0 + rr) * 36 + cg * 9 + c] = acc[rr][c];
            Hs[rt * 2 + rr][cg * 9 + c] = acc[rr][c];
        }
    __syncthreads();
    if (t < 128) {
        int row = blockIdx.x * 128 + t;
        float h0 = Hs[t][0], h1 = Hs[t][1], h2v = Hs[t][2], h3 = Hs[t][3];
        sv[row]          = h0 * a_sent[0] + h1 * a_sent[1];
        sv[25600 + row]  = h0 * a_sent[2] + h1 * a_sent[3];
        sv[51200 + row]  = h2v * a_para[0] + h3 * a_para[1];
        sv[76800 + row]  = h2v * a_para[2] + h3 * a_para[3];
        float aq1 = 0.f, aq2 = 0.f;
#pragma unroll
        for (int o = 0; o < 32; ++o) {
            float hv = Hs[t][4 + o];
            aq1 += hv * a_q[o];
            aq2 += hv * a_q[32 + o];
        }
        sv[102400 + row] = aq1;
        sv[128000 + row] = aq2;
    }
}

// ---------------------------------------------------------------- sent+para attention + q attention (grid y: 0,1=sp chunks, 2=q)

__global__ __launch_bounds__(256) void attn_spq(const float* __restrict__ H2,
                                                const float* __restrict__ sv,
                                                const unsigned int* __restrict__ maskw,
                                                const float* __restrict__ bns_g, const float* __restrict__ bns_b,
                                                const float* __restrict__ bnp_g, const float* __restrict__ bnp_b,
                                                const float* __restrict__ bnq_g, const float* __restrict__ bnq_b,
                                                const float* __restrict__ W2, float* __restrict__ out) {
    int b = blockIdx.x;
    int t = threadIdx.x;
    if (blockIdx.y == 2) {
        __shared__ float p_lds[200];
        __shared__ float redd[4];
        __shared__ float red2[256];
        float s1v = sv[102400 + b * 200];
        float p = 0.f;
        if (t < 200) {
            unsigned int mw = maskw[(size_t)(b * 200) * 8 + (t >> 5)];
            if ((mw >> (t & 31)) & 1u) {
                float x = s1v + sv[128000 + b * 200 + t];
                x = fmaxf(x, 0.3f * x);
                p = __expf(x - EXP_SHIFT);
            }
            p_lds[t] = p;
        }
        float ds = p;
        for (int off = 32; off; off >>= 1) ds += __shfl_xor(ds, off, 64);
        if ((t & 63) == 0) redd[t >> 6] = ds;
        __syncthreads();
        ds = redd[0] + redd[1] + redd[2] + redd[3];
        int o = t & 31, g = t >> 5;
        float acc = 0.f;
        for (int j = g; j < 200; j += 8)
            acc += p_lds[j] * H2[(size_t)(b * 200 + j) * 36 + 4 + o];
        red2[t] = acc;
        __syncthreads();
        if (t < 32) {
            float s = 0.f;
#pragma unroll
            for (int gg = 0; gg < 8; ++gg) s += red2[gg * 32 + t];
            float qv = (s / ds) * (BN_SCALEF * bnq_g[0]) + bnq_b[0];
            float c0 = qv * W2[t * 2], c1 = qv * W2[t * 2 + 1];
#pragma unroll
            for (int off = 16; off; off >>= 1) {
                c0 += __shfl_xor(c0, off, 64);
                c1 += __shfl_xor(c1, off, 64);
            }
            if (t == 0) {
                out[102400 + b * 2 + 0] = c0 > 0.f ? c0 : __expf(c0) - 1.f;
                out[102400 + b * 2 + 1] = c0 == c0 ? (c1 > 0.f ? c1 : __expf(c1) - 1.f) : 0.f;
            }
        }
        return;
    }
    __shared__ float s2s[200], s2p[200];
    __shared__ __align__(16) float hsp[200 * 4];
    int chunk = blockIdx.y;
    if (t < 200) {
        s2s[t] = sv[25600 + b * 200 + t];
        s2p[t] = sv[76800 + b * 200 + t];
    }
    for (int idx = t; idx < 800; idx += 256) {
        int j = idx >> 2, c = idx & 3;
        hsp[idx] = H2[(size_t)(b * 200 + j) * 36 + c];
    }
    __syncthreads();
    int w = t >> 6, lane = t & 63;
    for (int it = 0; it < 25; ++it) {
        int i = chunk * 100 + it * 4 + w;
        float s1sv = sv[b * 200 + i];
        float s1pv = sv[51200 + b * 200 + i];
        float ds = 0.f, dp = 0.f, pa0 = 0.f, pa1 = 0.f, pb0 = 0.f, pb1 = 0.f;
#pragma unroll
        for (int q = 0; q < 4; ++q) {
            int j = lane + 64 * q;
            if (j < 200) {
                unsigned int mw = maskw[(size_t)(b * 200 + i) * 8 + (j >> 5)];
                if ((mw >> (j & 31)) & 1u) {
                    float x1 = s1sv + s2s[j]; x1 = fmaxf(x1, 0.3f * x1);
                    float x2 = s1pv + s2p[j]; x2 = fmaxf(x2, 0.3f * x2);
                    float p1 = __expf(x1 - EXP_SHIFT), p2 = __expf(x2 - EXP_SHIFT);
                    ds += p1; dp += p2;
                    float4 hv = *(float4*)&hsp[j * 4];
                    pa0 += p1 * hv.x; pa1 += p1 * hv.y;
                    pb0 += p2 * hv.z; pb1 += p2 * hv.w;
                }
            }
        }
        for (int off = 32; off; off >>= 1) {
            ds  += __shfl_xor(ds, off, 64);  dp  += __shfl_xor(dp, off, 64);
            pa0 += __shfl_xor(pa0, off, 64); pa1 += __shfl_xor(pa1, off, 64);
            pb0 += __shfl_xor(pb0, off, 64); pb1 += __shfl_xor(pb1, off, 64);
        }
        if (lane == 0) {
            float gs = BN_SCALEF * bns_g[i], bs = bns_b[i];
            float v0 = (pa0 / ds) * gs + bs, v1 = (pa1 / ds) * gs + bs;
            out[(size_t)(b * 200 + i) * 2 + 0] = 1.f / (1.f + __expf(-v0));
            out[(size_t)(b * 200 + i) * 2 + 1] = 1.f / (1.f + __expf(-v1));
            float gp = BN_SCALEF * bnp_g[i], bp = bnp_b[i];
            float u0 = (pb0 / dp) * gp + bp, u1 = (pb1 / dp) * gp + bp;
            out[51200 + (size_t)(b * 200 + i) * 2 + 0] = u0 > 0.f ? u0 : __expf(u0) - 1.f;
            out[51200 + (size_t)(b * 200 + i) * 2 + 1] = u1 > 0.f ? u1 : __expf(u1) - 1.f;
        }
    }
}

// ---------------------------------------------------------------- launch

extern "C" void kernel_launch(void* const* d_in, const int* in_sizes, int n_in,
                              void* d_out, int out_size, void* d_ws, size_t ws_size,
                              hipStream_t stream) {
    (void)in_sizes; (void)n_in; (void)out_size; (void)ws_size;
    const float* feat    = (const float*)d_in[0];
    const int*   adj     = (const int*)d_in[1];
    const float* W_heads = (const float*)d_in[2];
    const float* a_heads = (const float*)d_in[3];
    const float* bnh_g   = (const float*)d_in[4];
    const float* bnh_b   = (const float*)d_in[5];
    const float* bnt_g   = (const float*)d_in[6];
    const float* bnt_b   = (const float*)d_in[7];
    const float* W_sent  = (const float*)d_in[8];
    const float* a_sent  = (const float*)d_in[9];
    const float* bns_g   = (const float*)d_in[10];
    const float* bns_b   = (const float*)d_in[11];
    const float* W_para  = (const float*)d_in[12];
    const float* a_para  = (const float*)d_in[13];
    const float* bnp_g   = (const float*)d_in[14];
    const float* bnp_b   = (const float*)d_in[15];
    const float* W_q     = (const float*)d_in[16];
    const float* a_q     = (const float*)d_in[17];
    const float* bnq_g   = (const float*)d_in[18];
    const float* bnq_b   = (const float*)d_in[19];
    const float* W2      = (const float*)d_in[20];
    float* out = (float*)d_out;
    float* ws  = (float*)d_ws;

    _Float16* h16 = (_Float16*)ws;              // 6,553,600 h = 3,276,800 f
    _Float16* x16 = (_Float16*)(ws + 3276800);  // 6,553,600 h
    float* w2t   = ws + 6553600;                // 9,216 f
    _Float16* Bt = (_Float16*)(ws + 6562816);   // 196,608 h = 98,304 f
    unsigned int* maskw = (unsigned int*)(ws + 6661120);  // 204,800 words
    float* h2    = ws + 6865920;                // 921,600 f
    float* sv    = ws + 7787520;                // 153,600 f (end ~31.8 MB)

    prep<<<dim3(1793), dim3(256), 0, stream>>>(adj, W_heads, W_sent, W_para, W_q,
                                               maskw, Bt, w2t);
    gemm1_mfma32<<<dim3(800), dim3(256), 0, stream>>>(feat, Bt, h16);
    attn_heads_mfma<<<dim3(1024), dim3(256), 0, stream>>>(h16, a_heads, maskw,
                                                          bnh_g, bnh_b, bnt_g, bnt_b, x16);
    gemm2s<<<dim3(200), dim3(256), 0, stream>>>(x16, w2t, a_sent, a_para, a_q, h2, sv);
    attn_spq<<<dim3(128, 3), dim3(256), 0, stream>>>(h2, sv, maskw, bns_g, bns_b,
                                                     bnp_g, bnp_b, bnq_g, bnq_b, W2, out);
}

// Round 7
// 393.789 us; speedup vs baseline: 1.0168x; 1.0168x over previous
//
#include <hip/hip_runtime.h>
#include <hip/hip_bf16.h>
#include <cstdint>

#define BN_SCALEF 0.99999500003749975f  // 1/sqrt(1+1e-5)
#define EXP_SHIFT 4.0f

// Problem constants: B=128, N=200, F=768, H=8, Fo=32, Fh=256

typedef _Float16 half8 __attribute__((ext_vector_type(8)));
typedef _Float16 half4 __attribute__((ext_vector_type(4)));
typedef float floatx4 __attribute__((ext_vector_type(4)));

// ---------------------------------------------------------------- prep: pack_mask + Wcat^T + W2t48 (one launch)
// blocks 0..1599: mask; 1600..1791: Wcat^T tiles; 1792: W2t48 (36 cols + 6 combined W@a cols + 6 zero)

__global__ __launch_bounds__(256) void prep(const int* __restrict__ adj,
                                            const float* __restrict__ W_heads,
                                            const float* __restrict__ Ws_in,
                                            const float* __restrict__ Wp_in,
                                            const float* __restrict__ Wq_in,
                                            const float* __restrict__ a_sent,
                                            const float* __restrict__ a_para,
                                            const float* __restrict__ a_q,
                                            unsigned int* __restrict__ maskw,
                                            _Float16* __restrict__ Bt,
                                            _Float16* __restrict__ W2t48) {
    int blk = blockIdx.x;
    int t = threadIdx.x;
    if (blk < 1600) {
        int w = t >> 6, lane = t & 63;
        for (int task = w; task < 64; task += 4) {
            int r = blk * 16 + (task >> 2);
            int c0 = (task & 3) * 64;
            int j = c0 + lane;
            bool v = (j < 200) && (adj[(size_t)r * 200 + j] > 0);
            unsigned long long m = __ballot(v ? 1 : 0);
            if (lane == 0) {
                maskw[r * 8 + (c0 >> 5)]     = (unsigned int)(m & 0xffffffffULL);
                maskw[r * 8 + (c0 >> 5) + 1] = (unsigned int)(m >> 32);
            }
        }
    } else if (blk < 1792) {
        __shared__ float ld[32][36];
        int blk2 = blk - 1600;          // h = blk2/24, f-tile = blk2%24
        int h = blk2 / 24, f0 = (blk2 % 24) * 32;
        int idx = t * 4;
        int fr = idx >> 5, o0 = idx & 31;
        float4 v = *(const float4*)&W_heads[(size_t)h * 24576 + (size_t)(f0 + fr) * 32 + o0];
        ld[fr][o0] = v.x; ld[fr][o0 + 1] = v.y; ld[fr][o0 + 2] = v.z; ld[fr][o0 + 3] = v.w;
        __syncthreads();
        int o = idx >> 5, fr0 = idx & 31;
        half4 hv;
#pragma unroll
        for (int u = 0; u < 4; ++u) hv[u] = (_Float16)ld[fr0 + u][o];
        *(half4*)&Bt[(size_t)(h * 32 + o) * 768 + f0 + fr0] = hv;
    } else {
        int k = t;  // 256
        for (int c = 0; c < 36; ++c) {
            float v;
            if (c < 2)      v = Ws_in[k * 2 + c];
            else if (c < 4) v = Wp_in[k * 2 + (c - 2)];
            else            v = Wq_in[k * 32 + (c - 4)];
            W2t48[c * 256 + k] = (_Float16)v;
        }
        // combined columns: (W @ a) so s1/s2 fall out of the GEMM directly
        W2t48[36 * 256 + k] = (_Float16)(Ws_in[k * 2] * a_sent[0] + Ws_in[k * 2 + 1] * a_sent[1]);
        W2t48[37 * 256 + k] = (_Float16)(Ws_in[k * 2] * a_sent[2] + Ws_in[k * 2 + 1] * a_sent[3]);
        W2t48[38 * 256 + k] = (_Float16)(Wp_in[k * 2] * a_para[0] + Wp_in[k * 2 + 1] * a_para[1]);
        W2t48[39 * 256 + k] = (_Float16)(Wp_in[k * 2] * a_para[2] + Wp_in[k * 2 + 1] * a_para[3]);
        float q1 = 0.f, q2 = 0.f;
#pragma unroll
        for (int o = 0; o < 32; ++o) {
            q1 += Wq_in[k * 32 + o] * a_q[o];
            q2 += Wq_in[k * 32 + o] * a_q[32 + o];
        }
        W2t48[40 * 256 + k] = (_Float16)q1;
        W2t48[41 * 256 + k] = (_Float16)q2;
        for (int c = 42; c < 48; ++c) W2t48[c * 256 + k] = (_Float16)0.f;
    }
}

// ---------------------------------------------------------------- GEMM1: 32x256 tile, BK=64, 16x16 MFMA, grid 800
// h16[25600,256] = A[25600,768] fp32 @ Bt^T (f16 [256][768])
// 256 thr = 4 waves; wave w = cols w*64 (2 row-tiles x 4 col-tiles of 16)

__global__ __launch_bounds__(256) void gemm1_k64(const float* __restrict__ A,
                                                 const _Float16* __restrict__ Bt,
                                                 _Float16* __restrict__ h16) {
    __shared__ __align__(16) _Float16 As[32 * 72];    // [row][k], pad 8
    __shared__ __align__(16) _Float16 Bs[256 * 72];   // [col][k], pad 8
    int t = threadIdx.x;
    int m0 = blockIdx.x * 32;       // 800 blocks
    int w = t >> 6, lane = t & 63;
    int quad = lane >> 4, l16 = lane & 15;
    int c0 = w * 64;

    floatx4 acc[2][4];
#pragma unroll
    for (int i = 0; i < 2; ++i)
#pragma unroll
        for (int j = 0; j < 4; ++j) acc[i][j] = (floatx4){0.f, 0.f, 0.f, 0.f};

    int arow = t >> 3, ako = (t & 7) * 8;      // A: 32 rows x 64 k, 2 float4/thread
    int bcol = t >> 3, bko = (t & 7) * 8;      // B: 8 chunks: col = bcol+32p, half8 each
    const float*    Aptr = &A[(size_t)(m0 + arow) * 768 + ako];
    const _Float16* Bptr = &Bt[(size_t)bcol * 768 + bko];

    float4 pa0 = *(const float4*)(Aptr);
    float4 pa1 = *(const float4*)(Aptr + 4);
    uint4 pb[8];
#pragma unroll
    for (int p = 0; p < 8; ++p)
        pb[p] = *(const uint4*)(Bptr + (size_t)p * 32 * 768);

    for (int kt = 0; kt < 12; ++kt) {
        half8 ah;
        ah[0] = (_Float16)pa0.x; ah[1] = (_Float16)pa0.y;
        ah[2] = (_Float16)pa0.z; ah[3] = (_Float16)pa0.w;
        ah[4] = (_Float16)pa1.x; ah[5] = (_Float16)pa1.y;
        ah[6] = (_Float16)pa1.z; ah[7] = (_Float16)pa1.w;
        *(half8*)&As[arow * 72 + ako] = ah;
#pragma unroll
        for (int p = 0; p < 8; ++p)
            *(uint4*)&Bs[(bcol + 32 * p) * 72 + bko] = pb[p];
        __syncthreads();
        if (kt < 11) {
            int ko = (kt + 1) * 64;
            pa0 = *(const float4*)(Aptr + ko);
            pa1 = *(const float4*)(Aptr + ko + 4);
#pragma unroll
            for (int p = 0; p < 8; ++p)
                pb[p] = *(const uint4*)(Bptr + (size_t)p * 32 * 768 + ko);
        }
#pragma unroll
        for (int kh = 0; kh < 2; ++kh) {
            half8 af[2], bf[4];
#pragma unroll
            for (int rt = 0; rt < 2; ++rt)
                af[rt] = *(half8*)&As[(rt * 16 + l16) * 72 + kh * 32 + quad * 8];
#pragma unroll
            for (int ct = 0; ct < 4; ++ct)
                bf[ct] = *(half8*)&Bs[(c0 + ct * 16 + l16) * 72 + kh * 32 + quad * 8];
#pragma unroll
            for (int rt = 0; rt < 2; ++rt)
#pragma unroll
                for (int ct = 0; ct < 4; ++ct)
                    acc[rt][ct] = __builtin_amdgcn_mfma_f32_16x16x32_f16(af[rt], bf[ct], acc[rt][ct], 0, 0, 0);
        }
        __syncthreads();
    }

#pragma unroll
    for (int rt = 0; rt < 2; ++rt)
#pragma unroll
        for (int ct = 0; ct < 4; ++ct) {
            int gc = c0 + ct * 16 + l16;
#pragma unroll
            for (int r = 0; r < 4; ++r) {
                int gr = m0 + rt * 16 + quad * 4 + r;
                h16[(size_t)gr * 256 + gc] = (_Float16)acc[rt][ct][r];
            }
        }
}

// ---------------------------------------------------------------- head attention via MFMA (h16 in, x16 out)

__global__ __launch_bounds__(256) void attn_heads_mfma(
    const _Float16* __restrict__ h16,
    const float* __restrict__ a_h,
    const unsigned int* __restrict__ maskw,
    const float* __restrict__ bnh_g, const float* __restrict__ bnh_b,
    const float* __restrict__ bnt_g, const float* __restrict__ bnt_b,
    _Float16* __restrict__ x16) {
    __shared__ __align__(16) _Float16 Bs[48 * 228];   // [n][k]: n<32 h^T, n=32 ones, rest 0
    __shared__ __align__(16) _Float16 Ps[64 * 228];   // 4 waves x 16-row slabs
    __shared__ float s1s[256], s2s[256];
    int hb = blockIdx.x;
    int h = hb >> 7, b = hb & 127;
    int t = threadIdx.x;

    unsigned long long* bz = (unsigned long long*)Bs;
    for (int idx = t; idx < (48 * 228) / 4; idx += 256) bz[idx] = 0ULL;
    __syncthreads();
    for (int idx = t; idx < 800; idx += 256) {
        int j = idx >> 2, w8 = (idx & 3) * 8;
        half8 v = *(const half8*)&h16[(size_t)(b * 200 + j) * 256 + h * 32 + w8];
#pragma unroll
        for (int u = 0; u < 8; ++u) Bs[(w8 + u) * 228 + j] = v[u];
    }
    if (t < 200) Bs[32 * 228 + t] = (_Float16)1.0f;
    __syncthreads();

    if (t < 200) {
        float acc1 = 0.f, acc2 = 0.f;
        const float* ab = &a_h[h * 64];
#pragma unroll
        for (int o = 0; o < 32; ++o) {
            float hv = (float)Bs[o * 228 + t];
            acc1 += hv * ab[o];
            acc2 += hv * ab[32 + o];
        }
        s1s[t] = acc1; s2s[t] = acc2;
    } else {
        s1s[t] = 0.f; s2s[t] = 0.f;
    }
    __syncthreads();

    int w = t >> 6, lane = t & 63;
    int l16 = lane & 15, quad = lane >> 4;
    _Float16* Pw = &Ps[w * 16 * 228];

    int j0 = lane * 4;
    float4 s2r = *(const float4*)&s2s[j0];

    for (int tile = w; tile < 13; tile += 4) {
        int i_base = tile * 16;
        int nrows = (i_base + 16 <= 200) ? 16 : (200 - i_base);
        unsigned int mwr[16];
        for (int r16 = 0; r16 < nrows; ++r16)
            mwr[r16] = maskw[(size_t)(b * 200 + i_base + r16) * 8 + (lane >> 3)];
        for (int r16 = 0; r16 < nrows; ++r16) {
            int i = i_base + r16;
            float s1v = s1s[i];
            unsigned int mw = mwr[r16];
            half4 pv;
#pragma unroll
            for (int q = 0; q < 4; ++q) {
                float e = s1v + ((const float*)&s2r)[q];
                e = fmaxf(e, 0.3f * e);
                float p = ((mw >> ((j0 + q) & 31)) & 1u) ? __expf(e - EXP_SHIFT) : 0.f;
                pv[q] = (_Float16)p;
            }
            if (j0 < 228) *(half4*)&Pw[r16 * 228 + j0] = pv;
        }
        floatx4 acc0 = {0.f, 0.f, 0.f, 0.f};
        floatx4 acc1 = {0.f, 0.f, 0.f, 0.f};
        floatx4 acc2 = {0.f, 0.f, 0.f, 0.f};
#pragma unroll
        for (int kt = 0; kt < 7; ++kt) {
            half8 af = *(half8*)&Pw[l16 * 228 + kt * 32 + quad * 8];
            half8 b0 = *(half8*)&Bs[(l16) * 228 + kt * 32 + quad * 8];
            half8 b1 = *(half8*)&Bs[(16 + l16) * 228 + kt * 32 + quad * 8];
            half8 b2 = *(half8*)&Bs[(32 + l16) * 228 + kt * 32 + quad * 8];
            acc0 = __builtin_amdgcn_mfma_f32_16x16x32_f16(af, b0, acc0, 0, 0, 0);
            acc1 = __builtin_amdgcn_mfma_f32_16x16x32_f16(af, b1, acc1, 0, 0, 0);
            acc2 = __builtin_amdgcn_mfma_f32_16x16x32_f16(af, b2, acc2, 0, 0, 0);
        }
#pragma unroll
        for (int r = 0; r < 4; ++r) {
            int i = i_base + quad * 4 + r;
            float rsum = __shfl(acc2[r], (lane & 48), 64);
            if (i < 200) {
                float inv = 1.f / rsum;
                float g1 = BN_SCALEF * bnh_g[h * 200 + i], c1 = bnh_b[h * 200 + i];
                float g2 = BN_SCALEF * bnt_g[i], c2 = bnt_b[i];
                float v0 = acc0[r] * inv * g1 + c1;
                v0 = v0 > 0.f ? v0 : __expf(v0) - 1.f;
                v0 = v0 * g2 + c2;
                float v1 = acc1[r] * inv * g1 + c1;
                v1 = v1 > 0.f ? v1 : __expf(v1) - 1.f;
                v1 = v1 * g2 + c2;
                size_t base = (size_t)(b * 200 + i) * 256 + h * 32;
                x16[base + l16]      = (_Float16)v0;
                x16[base + 16 + l16] = (_Float16)v1;
            }
        }
    }
}

// ---------------------------------------------------------------- GEMM2 via MFMA: H2p[25600][48] = x16 @ W2t48^T
// block = 64 rows, 4 waves x 16 rows; K=256 fully staged, one barrier.

__global__ __launch_bounds__(256) void gemm2m(const _Float16* __restrict__ X,
                                              const _Float16* __restrict__ Wt,
                                              float* __restrict__ H2p) {
    __shared__ __align__(16) _Float16 Xs[64 * 264];   // [row][k], pad 8
    __shared__ __align__(16) _Float16 Ws[48 * 264];
    int t = threadIdx.x;
    int m0 = blockIdx.x * 64;       // 400 blocks
#pragma unroll
    for (int p = 0; p < 8; ++p) {
        int g = t + 256 * p;                 // 2048 half8 chunks
        int row = g >> 5, ko = (g & 31) * 8;
        *(half8*)&Xs[row * 264 + ko] = *(const half8*)&X[(size_t)(m0 + row) * 256 + ko];
    }
#pragma unroll
    for (int p = 0; p < 6; ++p) {
        int g = t + 256 * p;                 // 1536 half8 chunks
        int n = g >> 5, ko = (g & 31) * 8;
        *(half8*)&Ws[n * 264 + ko] = *(const half8*)&Wt[(size_t)n * 256 + ko];
    }
    __syncthreads();

    int w = t >> 6, lane = t & 63;
    int l16 = lane & 15, quad = lane >> 4;
    int rbase = w * 16;
    floatx4 acc[3];
#pragma unroll
    for (int c = 0; c < 3; ++c) acc[c] = (floatx4){0.f, 0.f, 0.f, 0.f};
#pragma unroll
    for (int kt = 0; kt < 8; ++kt) {
        half8 af = *(half8*)&Xs[(rbase + l16) * 264 + kt * 32 + quad * 8];
#pragma unroll
        for (int ct = 0; ct < 3; ++ct) {
            half8 bf = *(half8*)&Ws[(ct * 16 + l16) * 264 + kt * 32 + quad * 8];
            acc[ct] = __builtin_amdgcn_mfma_f32_16x16x32_f16(af, bf, acc[ct], 0, 0, 0);
        }
    }
#pragma unroll
    for (int ct = 0; ct < 3; ++ct) {
        int col = ct * 16 + l16;
#pragma unroll
        for (int r = 0; r < 4; ++r) {
            int row = m0 + rbase + quad * 4 + r;
            H2p[(size_t)row * 48 + col] = acc[ct][r];
        }
    }
}

// ---------------------------------------------------------------- sent+para+q attention
// H2p cols: 0-1 sent h2, 2-3 para h2, 4-35 q h2, 36/37 s1/s2 sent, 38/39 para, 40/41 q

__global__ __launch_bounds__(256) void attn_spq(const float* __restrict__ H2p,
                                                const unsigned int* __restrict__ maskw,
                                                const float* __restrict__ bns_g, const float* __restrict__ bns_b,
                                                const float* __restrict__ bnp_g, const float* __restrict__ bnp_b,
                                                const float* __restrict__ bnq_g, const float* __restrict__ bnq_b,
                                                const float* __restrict__ W2, float* __restrict__ out) {
    int b = blockIdx.x;
    int t = threadIdx.x;
    if (blockIdx.y == 2) {
        __shared__ float p_lds[200];
        __shared__ float redd[4];
        __shared__ float red2[256];
        float s1v = H2p[(size_t)(b * 200) * 48 + 40];
        float p = 0.f;
        if (t < 200) {
            unsigned int mw = maskw[(size_t)(b * 200) * 8 + (t >> 5)];
            if ((mw >> (t & 31)) & 1u) {
                float x = s1v + H2p[(size_t)(b * 200 + t) * 48 + 41];
                x = fmaxf(x, 0.3f * x);
                p = __expf(x - EXP_SHIFT);
            }
            p_lds[t] = p;
        }
        float ds = p;
        for (int off = 32; off; off >>= 1) ds += __shfl_xor(ds, off, 64);
        if ((t & 63) == 0) redd[t >> 6] = ds;
        __syncthreads();
        ds = redd[0] + redd[1] + redd[2] + redd[3];
        int o = t & 31, g = t >> 5;
        float acc = 0.f;
        for (int j = g; j < 200; j += 8)
            acc += p_lds[j] * H2p[(size_t)(b * 200 + j) * 48 + 4 + o];
        red2[t] = acc;
        __syncthreads();
        if (t < 32) {
            float s = 0.f;
#pragma unroll
            for (int gg = 0; gg < 8; ++gg) s += red2[gg * 32 + t];
            float qv = (s / ds) * (BN_SCALEF * bnq_g[0]) + bnq_b[0];
            float c0 = qv * W2[t * 2], c1 = qv * W2[t * 2 + 1];
#pragma unroll
            for (int off = 16; off; off >>= 1) {
                c0 += __shfl_xor(c0, off, 64);
                c1 += __shfl_xor(c1, off, 64);
            }
            if (t == 0) {
                out[102400 + b * 2 + 0] = c0 > 0.f ? c0 : __expf(c0) - 1.f;
                out[102400 + b * 2 + 1] = c1 > 0.f ? c1 : __expf(c1) - 1.f;
            }
        }
        return;
    }
    __shared__ float s2s[200], s2p[200];
    __shared__ float s1sA[200], s1pA[200];
    __shared__ __align__(16) float hsp[200 * 4];
    int chunk = blockIdx.y;
    if (t < 200) {
        const float* hr = &H2p[(size_t)(b * 200 + t) * 48];
        float4 hv = *(const float4*)hr;
        *(float4*)&hsp[t * 4] = hv;
        s1sA[t] = hr[36]; s2s[t] = hr[37];
        s1pA[t] = hr[38]; s2p[t] = hr[39];
    }
    __syncthreads();
    int w = t >> 6, lane = t & 63;
    for (int it = 0; it < 25; ++it) {
        int i = chunk * 100 + it * 4 + w;
        float s1sv = s1sA[i];
        float s1pv = s1pA[i];
        float ds = 0.f, dp = 0.f, pa0 = 0.f, pa1 = 0.f, pb0 = 0.f, pb1 = 0.f;
#pragma unroll
        for (int q = 0; q < 4; ++q) {
            int j = lane + 64 * q;
            if (j < 200) {
                unsigned int mw = maskw[(size_t)(b * 200 + i) * 8 + (j >> 5)];
                if ((mw >> (j & 31)) & 1u) {
                    float x1 = s1sv + s2s[j]; x1 = fmaxf(x1, 0.3f * x1);
                    float x2 = s1pv + s2p[j]; x2 = fmaxf(x2, 0.3f * x2);
                    float p1 = __expf(x1 - EXP_SHIFT), p2 = __expf(x2 - EXP_SHIFT);
                    ds += p1; dp += p2;
                    float4 hv = *(float4*)&hsp[j * 4];
                    pa0 += p1 * hv.x; pa1 += p1 * hv.y;
                    pb0 += p2 * hv.z; pb1 += p2 * hv.w;
                }
            }
        }
        for (int off = 32; off; off >>= 1) {
            ds  += __shfl_xor(ds, off, 64);  dp  += __shfl_xor(dp, off, 64);
            pa0 += __shfl_xor(pa0, off, 64); pa1 += __shfl_xor(pa1, off, 64);
            pb0 += __shfl_xor(pb0, off, 64); pb1 += __shfl_xor(pb1, off, 64);
        }
        if (lane == 0) {
            float gs = BN_SCALEF * bns_g[i], bs = bns_b[i];
            float v0 = (pa0 / ds) * gs + bs, v1 = (pa1 / ds) * gs + bs;
            out[(size_t)(b * 200 + i) * 2 + 0] = 1.f / (1.f + __expf(-v0));
            out[(size_t)(b * 200 + i) * 2 + 1] = 1.f / (1.f + __expf(-v1));
            float gp = BN_SCALEF * bnp_g[i], bp = bnp_b[i];
            float u0 = (pb0 / dp) * gp + bp, u1 = (pb1 / dp) * gp + bp;
            out[51200 + (size_t)(b * 200 + i) * 2 + 0] = u0 > 0.f ? u0 : __expf(u0) - 1.f;
            out[51200 + (size_t)(b * 200 + i) * 2 + 1] = u1 > 0.f ? u1 : __expf(u1) - 1.f;
        }
    }
}

// ---------------------------------------------------------------- launch

extern "C" void kernel_launch(void* const* d_in, const int* in_sizes, int n_in,
                              void* d_out, int out_size, void* d_ws, size_t ws_size,
                              hipStream_t stream) {
    (void)in_sizes; (void)n_in; (void)out_size; (void)ws_size;
    const float* feat    = (const float*)d_in[0];
    const int*   adj     = (const int*)d_in[1];
    const float* W_heads = (const float*)d_in[2];
    const float* a_heads = (const float*)d_in[3];
    const float* bnh_g   = (const float*)d_in[4];
    const float* bnh_b   = (const float*)d_in[5];
    const float* bnt_g   = (const float*)d_in[6];
    const float* bnt_b   = (const float*)d_in[7];
    const float* W_sent  = (const float*)d_in[8];
    const float* a_sent  = (const float*)d_in[9];
    const float* bns_g   = (const float*)d_in[10];
    const float* bns_b   = (const float*)d_in[11];
    const float* W_para  = (const float*)d_in[12];
    const float* a_para  = (const float*)d_in[13];
    const float* bnp_g   = (const float*)d_in[14];
    const float* bnp_b   = (const float*)d_in[15];
    const float* W_q     = (const float*)d_in[16];
    const float* a_q     = (const float*)d_in[17];
    const float* bnq_g   = (const float*)d_in[18];
    const float* bnq_b   = (const float*)d_in[19];
    const float* W2      = (const float*)d_in[20];
    float* out = (float*)d_out;
    float* ws  = (float*)d_ws;

    _Float16* h16   = (_Float16*)ws;              // 6,553,600 h = 3,276,800 f
    _Float16* x16   = (_Float16*)(ws + 3276800);  // 6,553,600 h
    _Float16* W2t48 = (_Float16*)(ws + 6553600);  // 12,288 h = 6,144 f
    _Float16* Bt    = (_Float16*)(ws + 6559744);  // 196,608 h = 98,304 f
    unsigned int* maskw = (unsigned int*)(ws + 6658048);  // 204,800 words
    float* H2p   = ws + 6862848;                  // 1,228,800 f (end ~32.4 MB)

    prep<<<dim3(1793), dim3(256), 0, stream>>>(adj, W_heads, W_sent, W_para, W_q,
                                               a_sent, a_para, a_q, maskw, Bt, W2t48);
    gemm1_k64<<<dim3(800), dim3(256), 0, stream>>>(feat, Bt, h16);
    attn_heads_mfma<<<dim3(1024), dim3(256), 0, stream>>>(h16, a_heads, maskw,
                                                          bnh_g, bnh_b, bnt_g, bnt_b, x16);
    gemm2m<<<dim3(400), dim3(256), 0, stream>>>(x16, W2t48, H2p);
    attn_spq<<<dim3(128, 3), dim3(256), 0, stream>>>(H2p, maskw, bns_g, bns_b,
                                                     bnp_g, bnp_b, bnq_g, bnq_b, W2, out);
}

// Round 8
// 307.044 us; speedup vs baseline: 1.3041x; 1.2825x over previous
//
#include <hip/hip_runtime.h>
#include <hip/hip_bf16.h>
#include <cstdint>

#define BN_SCALEF 0.99999500003749975f  // 1/sqrt(1+1e-5)
#define EXP_SHIFT 4.0f

// Problem constants: B=128, N=200, F=768, H=8, Fo=32, Fh=256

typedef _Float16 half8 __attribute__((ext_vector_type(8)));
typedef _Float16 half4 __attribute__((ext_vector_type(4)));
typedef float floatx4 __attribute__((ext_vector_type(4)));

// ---------------------------------------------------------------- prep: pack_mask + Wcat^T + W2t48 (one launch)

__global__ __launch_bounds__(256) void prep(const int* __restrict__ adj,
                                            const float* __restrict__ W_heads,
                                            const float* __restrict__ Ws_in,
                                            const float* __restrict__ Wp_in,
                                            const float* __restrict__ Wq_in,
                                            const float* __restrict__ a_sent,
                                            const float* __restrict__ a_para,
                                            const float* __restrict__ a_q,
                                            unsigned int* __restrict__ maskw,
                                            _Float16* __restrict__ Bt,
                                            _Float16* __restrict__ W2t48) {
    int blk = blockIdx.x;
    int t = threadIdx.x;
    if (blk < 1600) {
        int w = t >> 6, lane = t & 63;
        for (int task = w; task < 64; task += 4) {
            int r = blk * 16 + (task >> 2);
            int c0 = (task & 3) * 64;
            int j = c0 + lane;
            bool v = (j < 200) && (adj[(size_t)r * 200 + j] > 0);
            unsigned long long m = __ballot(v ? 1 : 0);
            if (lane == 0) {
                maskw[r * 8 + (c0 >> 5)]     = (unsigned int)(m & 0xffffffffULL);
                maskw[r * 8 + (c0 >> 5) + 1] = (unsigned int)(m >> 32);
            }
        }
    } else if (blk < 1792) {
        __shared__ float ld[32][36];
        int blk2 = blk - 1600;          // h = blk2/24, f-tile = blk2%24
        int h = blk2 / 24, f0 = (blk2 % 24) * 32;
        int idx = t * 4;
        int fr = idx >> 5, o0 = idx & 31;
        float4 v = *(const float4*)&W_heads[(size_t)h * 24576 + (size_t)(f0 + fr) * 32 + o0];
        ld[fr][o0] = v.x; ld[fr][o0 + 1] = v.y; ld[fr][o0 + 2] = v.z; ld[fr][o0 + 3] = v.w;
        __syncthreads();
        int o = idx >> 5, fr0 = idx & 31;
        half4 hv;
#pragma unroll
        for (int u = 0; u < 4; ++u) hv[u] = (_Float16)ld[fr0 + u][o];
        *(half4*)&Bt[(size_t)(h * 32 + o) * 768 + f0 + fr0] = hv;
    } else {
        int k = t;  // 256
        for (int c = 0; c < 36; ++c) {
            float v;
            if (c < 2)      v = Ws_in[k * 2 + c];
            else if (c < 4) v = Wp_in[k * 2 + (c - 2)];
            else            v = Wq_in[k * 32 + (c - 4)];
            W2t48[c * 256 + k] = (_Float16)v;
        }
        W2t48[36 * 256 + k] = (_Float16)(Ws_in[k * 2] * a_sent[0] + Ws_in[k * 2 + 1] * a_sent[1]);
        W2t48[37 * 256 + k] = (_Float16)(Ws_in[k * 2] * a_sent[2] + Ws_in[k * 2 + 1] * a_sent[3]);
        W2t48[38 * 256 + k] = (_Float16)(Wp_in[k * 2] * a_para[0] + Wp_in[k * 2 + 1] * a_para[1]);
        W2t48[39 * 256 + k] = (_Float16)(Wp_in[k * 2] * a_para[2] + Wp_in[k * 2 + 1] * a_para[3]);
        float q1 = 0.f, q2 = 0.f;
#pragma unroll
        for (int o = 0; o < 32; ++o) {
            q1 += Wq_in[k * 32 + o] * a_q[o];
            q2 += Wq_in[k * 32 + o] * a_q[32 + o];
        }
        W2t48[40 * 256 + k] = (_Float16)q1;
        W2t48[41 * 256 + k] = (_Float16)q2;
        for (int c = 42; c < 48; ++c) W2t48[c * 256 + k] = (_Float16)0.f;
    }
}

// ---------------------------------------------------------------- GEMM1: 32x256 tile, BK=32, 16x16 MFMA, grid 800
// h16[25600,256] = A[25600,768] fp32 @ Bt^T (f16 [256][768])
// 256 thr = 4 waves; wave w = cols w*64 (2 row-tiles x 4 col-tiles of 16).
// Named prefetch regs (pb0..pb3) — R7's pb[8] spilled to scratch (203 MB writes).

__global__ __launch_bounds__(256) void gemm1_s(const float* __restrict__ A,
                                               const _Float16* __restrict__ Bt,
                                               _Float16* __restrict__ h16) {
    __shared__ __align__(16) _Float16 As[32 * 40];    // [row][k], pad 8
    __shared__ __align__(16) _Float16 Bs[256 * 40];   // [col][k], pad 8
    int t = threadIdx.x;
    int m0 = blockIdx.x * 32;       // 800 blocks
    int w = t >> 6, lane = t & 63;
    int quad = lane >> 4, l16 = lane & 15;
    int c0 = w * 64;

    floatx4 acc[2][4];
#pragma unroll
    for (int i = 0; i < 2; ++i)
#pragma unroll
        for (int j = 0; j < 4; ++j) acc[i][j] = (floatx4){0.f, 0.f, 0.f, 0.f};

    int arow = t >> 3, ako = (t & 7) * 4;      // A: 32 rows x 32 k, one float4/thread
    int bcol = t >> 2, bko = (t & 3) * 8;      // B: 4 planes of 64 cols, one half8/thread
    const float*    Aptr = &A[(size_t)(m0 + arow) * 768 + ako];
    const _Float16* Bptr = &Bt[(size_t)bcol * 768 + bko];

    float4 pa  = *(const float4*)Aptr;
    uint4 pb0 = *(const uint4*)(Bptr);
    uint4 pb1 = *(const uint4*)(Bptr + 64 * 768);
    uint4 pb2 = *(const uint4*)(Bptr + 128 * 768);
    uint4 pb3 = *(const uint4*)(Bptr + 192 * 768);

    for (int kt = 0; kt < 24; ++kt) {
        half4 ah;
        ah[0] = (_Float16)pa.x; ah[1] = (_Float16)pa.y;
        ah[2] = (_Float16)pa.z; ah[3] = (_Float16)pa.w;
        *(half4*)&As[arow * 40 + ako] = ah;
        *(uint4*)&Bs[(bcol) * 40 + bko]       = pb0;
        *(uint4*)&Bs[(64 + bcol) * 40 + bko]  = pb1;
        *(uint4*)&Bs[(128 + bcol) * 40 + bko] = pb2;
        *(uint4*)&Bs[(192 + bcol) * 40 + bko] = pb3;
        __syncthreads();
        if (kt < 23) {
            int ko = (kt + 1) * 32;
            pa  = *(const float4*)(Aptr + ko);
            pb0 = *(const uint4*)(Bptr + ko);
            pb1 = *(const uint4*)(Bptr + 64 * 768 + ko);
            pb2 = *(const uint4*)(Bptr + 128 * 768 + ko);
            pb3 = *(const uint4*)(Bptr + 192 * 768 + ko);
        }
        half8 af[2], bf[4];
#pragma unroll
        for (int rt = 0; rt < 2; ++rt)
            af[rt] = *(half8*)&As[(rt * 16 + l16) * 40 + quad * 8];
#pragma unroll
        for (int ct = 0; ct < 4; ++ct)
            bf[ct] = *(half8*)&Bs[(c0 + ct * 16 + l16) * 40 + quad * 8];
#pragma unroll
        for (int rt = 0; rt < 2; ++rt)
#pragma unroll
            for (int ct = 0; ct < 4; ++ct)
                acc[rt][ct] = __builtin_amdgcn_mfma_f32_16x16x32_f16(af[rt], bf[ct], acc[rt][ct], 0, 0, 0);
        __syncthreads();
    }

#pragma unroll
    for (int rt = 0; rt < 2; ++rt)
#pragma unroll
        for (int ct = 0; ct < 4; ++ct) {
            int gc = c0 + ct * 16 + l16;
#pragma unroll
            for (int r = 0; r < 4; ++r) {
                int gr = m0 + rt * 16 + quad * 4 + r;
                h16[(size_t)gr * 256 + gc] = (_Float16)acc[rt][ct][r];
            }
        }
}

// ---------------------------------------------------------------- head attention via MFMA (h16 in, x16 head-major out)
// x16h layout [h][25600][32]: each block writes a contiguous 12.8 KB region (full lines).

__global__ __launch_bounds__(256) void attn_heads_mfma(
    const _Float16* __restrict__ h16,
    const float* __restrict__ a_h,
    const unsigned int* __restrict__ maskw,
    const float* __restrict__ bnh_g, const float* __restrict__ bnh_b,
    const float* __restrict__ bnt_g, const float* __restrict__ bnt_b,
    _Float16* __restrict__ x16h) {
    __shared__ __align__(16) _Float16 Bs[48 * 228];   // [n][k]: n<32 h^T, n=32 ones, rest 0
    __shared__ __align__(16) _Float16 Ps[64 * 228];   // 4 waves x 16-row slabs
    __shared__ float s1s[256], s2s[256];
    int hb = blockIdx.x;
    int h = hb >> 7, b = hb & 127;
    int t = threadIdx.x;

    unsigned long long* bz = (unsigned long long*)Bs;
    for (int idx = t; idx < (48 * 228) / 4; idx += 256) bz[idx] = 0ULL;
    __syncthreads();
    for (int idx = t; idx < 800; idx += 256) {
        int j = idx >> 2, w8 = (idx & 3) * 8;
        half8 v = *(const half8*)&h16[(size_t)(b * 200 + j) * 256 + h * 32 + w8];
#pragma unroll
        for (int u = 0; u < 8; ++u) Bs[(w8 + u) * 228 + j] = v[u];
    }
    if (t < 200) Bs[32 * 228 + t] = (_Float16)1.0f;
    __syncthreads();

    if (t < 200) {
        float acc1 = 0.f, acc2 = 0.f;
        const float* ab = &a_h[h * 64];
#pragma unroll
        for (int o = 0; o < 32; ++o) {
            float hv = (float)Bs[o * 228 + t];
            acc1 += hv * ab[o];
            acc2 += hv * ab[32 + o];
        }
        s1s[t] = acc1; s2s[t] = acc2;
    } else {
        s1s[t] = 0.f; s2s[t] = 0.f;
    }
    __syncthreads();

    int w = t >> 6, lane = t & 63;
    int l16 = lane & 15, quad = lane >> 4;
    _Float16* Pw = &Ps[w * 16 * 228];

    int j0 = lane * 4;
    float4 s2r = *(const float4*)&s2s[j0];

    for (int tile = w; tile < 13; tile += 4) {
        int i_base = tile * 16;
        int nrows = (i_base + 16 <= 200) ? 16 : (200 - i_base);
        unsigned int mwr[16];
        for (int r16 = 0; r16 < nrows; ++r16)
            mwr[r16] = maskw[(size_t)(b * 200 + i_base + r16) * 8 + (lane >> 3)];
        for (int r16 = 0; r16 < nrows; ++r16) {
            int i = i_base + r16;
            float s1v = s1s[i];
            unsigned int mw = mwr[r16];
            half4 pv;
#pragma unroll
            for (int q = 0; q < 4; ++q) {
                float e = s1v + ((const float*)&s2r)[q];
                e = fmaxf(e, 0.3f * e);
                float p = ((mw >> ((j0 + q) & 31)) & 1u) ? __expf(e - EXP_SHIFT) : 0.f;
                pv[q] = (_Float16)p;
            }
            if (j0 < 228) *(half4*)&Pw[r16 * 228 + j0] = pv;
        }
        floatx4 acc0 = {0.f, 0.f, 0.f, 0.f};
        floatx4 acc1 = {0.f, 0.f, 0.f, 0.f};
        floatx4 acc2 = {0.f, 0.f, 0.f, 0.f};
#pragma unroll
        for (int kt = 0; kt < 7; ++kt) {
            half8 af = *(half8*)&Pw[l16 * 228 + kt * 32 + quad * 8];
            half8 b0 = *(half8*)&Bs[(l16) * 228 + kt * 32 + quad * 8];
            half8 b1 = *(half8*)&Bs[(16 + l16) * 228 + kt * 32 + quad * 8];
            half8 b2 = *(half8*)&Bs[(32 + l16) * 228 + kt * 32 + quad * 8];
            acc0 = __builtin_amdgcn_mfma_f32_16x16x32_f16(af, b0, acc0, 0, 0, 0);
            acc1 = __builtin_amdgcn_mfma_f32_16x16x32_f16(af, b1, acc1, 0, 0, 0);
            acc2 = __builtin_amdgcn_mfma_f32_16x16x32_f16(af, b2, acc2, 0, 0, 0);
        }
#pragma unroll
        for (int r = 0; r < 4; ++r) {
            int i = i_base + quad * 4 + r;
            float rsum = __shfl(acc2[r], (lane & 48), 64);
            if (i < 200) {
                float inv = 1.f / rsum;
                float g1 = BN_SCALEF * bnh_g[h * 200 + i], c1 = bnh_b[h * 200 + i];
                float g2 = BN_SCALEF * bnt_g[i], c2 = bnt_b[i];
                float v0 = acc0[r] * inv * g1 + c1;
                v0 = v0 > 0.f ? v0 : __expf(v0) - 1.f;
                v0 = v0 * g2 + c2;
                float v1 = acc1[r] * inv * g1 + c1;
                v1 = v1 > 0.f ? v1 : __expf(v1) - 1.f;
                v1 = v1 * g2 + c2;
                size_t base = (size_t)h * 819200 + (size_t)(b * 200 + i) * 32;
                x16h[base + l16]      = (_Float16)v0;
                x16h[base + 16 + l16] = (_Float16)v1;
            }
        }
    }
}

// ---------------------------------------------------------------- GEMM2 via MFMA: H2p[25600][48] = x16h @ W2t48^T
// x16h gathered per head-plane; K=256 staged once, one barrier.

__global__ __launch_bounds__(256) void gemm2m(const _Float16* __restrict__ Xh,
                                              const _Float16* __restrict__ Wt,
                                              float* __restrict__ H2p) {
    __shared__ __align__(16) _Float16 Xs[64 * 264];   // [row][k = h*32+o], pad 8
    __shared__ __align__(16) _Float16 Ws[48 * 264];
    int t = threadIdx.x;
    int m0 = blockIdx.x * 64;       // 400 blocks
    int srow = t >> 2, schunk = (t & 3) * 8;
#pragma unroll
    for (int h = 0; h < 8; ++h) {
        half8 v = *(const half8*)&Xh[(size_t)h * 819200 + (size_t)(m0 + srow) * 32 + schunk];
        *(half8*)&Xs[srow * 264 + h * 32 + schunk] = v;
    }
#pragma unroll
    for (int p = 0; p < 6; ++p) {
        int g = t + 256 * p;                 // 1536 half8 chunks
        int n = g >> 5, ko = (g & 31) * 8;
        *(half8*)&Ws[n * 264 + ko] = *(const half8*)&Wt[(size_t)n * 256 + ko];
    }
    __syncthreads();

    int w = t >> 6, lane = t & 63;
    int l16 = lane & 15, quad = lane >> 4;
    int rbase = w * 16;
    floatx4 acc[3];
#pragma unroll
    for (int c = 0; c < 3; ++c) acc[c] = (floatx4){0.f, 0.f, 0.f, 0.f};
#pragma unroll
    for (int kt = 0; kt < 8; ++kt) {
        half8 af = *(half8*)&Xs[(rbase + l16) * 264 + kt * 32 + quad * 8];
#pragma unroll
        for (int ct = 0; ct < 3; ++ct) {
            half8 bf = *(half8*)&Ws[(ct * 16 + l16) * 264 + kt * 32 + quad * 8];
            acc[ct] = __builtin_amdgcn_mfma_f32_16x16x32_f16(af, bf, acc[ct], 0, 0, 0);
        }
    }
#pragma unroll
    for (int ct = 0; ct < 3; ++ct) {
        int col = ct * 16 + l16;
#pragma unroll
        for (int r = 0; r < 4; ++r) {
            int row = m0 + rbase + quad * 4 + r;
            H2p[(size_t)row * 48 + col] = acc[ct][r];
        }
    }
}

// ---------------------------------------------------------------- sent+para+q attention
// H2p cols: 0-1 sent h2, 2-3 para h2, 4-35 q h2, 36/37 s1/s2 sent, 38/39 para, 40/41 q

__global__ __launch_bounds__(256) void attn_spq(const float* __restrict__ H2p,
                                                const unsigned int* __restrict__ maskw,
                                                const float* __restrict__ bns_g, const float* __restrict__ bns_b,
                                                const float* __restrict__ bnp_g, const float* __restrict__ bnp_b,
                                                const float* __restrict__ bnq_g, const float* __restrict__ bnq_b,
                                                const float* __restrict__ W2, float* __restrict__ out) {
    int b = blockIdx.x;
    int t = threadIdx.x;
    if (blockIdx.y == 2) {
        __shared__ float p_lds[200];
        __shared__ float redd[4];
        __shared__ float red2[256];
        float s1v = H2p[(size_t)(b * 200) * 48 + 40];
        float p = 0.f;
        if (t < 200) {
            unsigned int mw = maskw[(size_t)(b * 200) * 8 + (t >> 5)];
            if ((mw >> (t & 31)) & 1u) {
                float x = s1v + H2p[(size_t)(b * 200 + t) * 48 + 41];
                x = fmaxf(x, 0.3f * x);
                p = __expf(x - EXP_SHIFT);
            }
            p_lds[t] = p;
        }
        float ds = p;
        for (int off = 32; off; off >>= 1) ds += __shfl_xor(ds, off, 64);
        if ((t & 63) == 0) redd[t >> 6] = ds;
        __syncthreads();
        ds = redd[0] + redd[1] + redd[2] + redd[3];
        int o = t & 31, g = t >> 5;
        float acc = 0.f;
        for (int j = g; j < 200; j += 8)
            acc += p_lds[j] * H2p[(size_t)(b * 200 + j) * 48 + 4 + o];
        red2[t] = acc;
        __syncthreads();
        if (t < 32) {
            float s = 0.f;
#pragma unroll
            for (int gg = 0; gg < 8; ++gg) s += red2[gg * 32 + t];
            float qv = (s / ds) * (BN_SCALEF * bnq_g[0]) + bnq_b[0];
            float c0 = qv * W2[t * 2], c1 = qv * W2[t * 2 + 1];
#pragma unroll
            for (int off = 16; off; off >>= 1) {
                c0 += __shfl_xor(c0, off, 64);
                c1 += __shfl_xor(c1, off, 64);
            }
            if (t == 0) {
                out[102400 + b * 2 + 0] = c0 > 0.f ? c0 : __expf(c0) - 1.f;
                out[102400 + b * 2 + 1] = c1 > 0.f ? c1 : __expf(c1) - 1.f;
            }
        }
        return;
    }
    __shared__ float s2s[200], s2p[200];
    __shared__ float s1sA[200], s1pA[200];
    __shared__ __align__(16) float hsp[200 * 4];
    int chunk = blockIdx.y;
    if (t < 200) {
        const float* hr = &H2p[(size_t)(b * 200 + t) * 48];
        float4 hv = *(const float4*)hr;
        *(float4*)&hsp[t * 4] = hv;
        s1sA[t] = hr[36]; s2s[t] = hr[37];
        s1pA[t] = hr[38]; s2p[t] = hr[39];
    }
    __syncthreads();
    int w = t >> 6, lane = t & 63;
    for (int it = 0; it < 25; ++it) {
        int i = chunk * 100 + it * 4 + w;
        float s1sv = s1sA[i];
        float s1pv = s1pA[i];
        float ds = 0.f, dp = 0.f, pa0 = 0.f, pa1 = 0.f, pb0 = 0.f, pb1 = 0.f;
#pragma unroll
        for (int q = 0; q < 4; ++q) {
            int j = lane + 64 * q;
            if (j < 200) {
                unsigned int mw = maskw[(size_t)(b * 200 + i) * 8 + (j >> 5)];
                if ((mw >> (j & 31)) & 1u) {
                    float x1 = s1sv + s2s[j]; x1 = fmaxf(x1, 0.3f * x1);
                    float x2 = s1pv + s2p[j]; x2 = fmaxf(x2, 0.3f * x2);
                    float p1 = __expf(x1 - EXP_SHIFT), p2 = __expf(x2 - EXP_SHIFT);
                    ds += p1; dp += p2;
                    float4 hv = *(float4*)&hsp[j * 4];
                    pa0 += p1 * hv.x; pa1 += p1 * hv.y;
                    pb0 += p2 * hv.z; pb1 += p2 * hv.w;
                }
            }
        }
        for (int off = 32; off; off >>= 1) {
            ds  += __shfl_xor(ds, off, 64);  dp  += __shfl_xor(dp, off, 64);
            pa0 += __shfl_xor(pa0, off, 64); pa1 += __shfl_xor(pa1, off, 64);
            pb0 += __shfl_xor(pb0, off, 64); pb1 += __shfl_xor(pb1, off, 64);
        }
        if (lane == 0) {
            float gs = BN_SCALEF * bns_g[i], bs = bns_b[i];
            float v0 = (pa0 / ds) * gs + bs, v1 = (pa1 / ds) * gs + bs;
            out[(size_t)(b * 200 + i) * 2 + 0] = 1.f / (1.f + __expf(-v0));
            out[(size_t)(b * 200 + i) * 2 + 1] = 1.f / (1.f + __expf(-v1));
            float gp = BN_SCALEF * bnp_g[i], bp = bnp_b[i];
            float u0 = (pb0 / dp) * gp + bp, u1 = (pb1 / dp) * gp + bp;
            out[51200 + (size_t)(b * 200 + i) * 2 + 0] = u0 > 0.f ? u0 : __expf(u0) - 1.f;
            out[51200 + (size_t)(b * 200 + i) * 2 + 1] = u1 > 0.f ? u1 : __expf(u1) - 1.f;
        }
    }
}

// ---------------------------------------------------------------- launch

extern "C" void kernel_launch(void* const* d_in, const int* in_sizes, int n_in,
                              void* d_out, int out_size, void* d_ws, size_t ws_size,
                              hipStream_t stream) {
    (void)in_sizes; (void)n_in; (void)out_size; (void)ws_size;
    const float* feat    = (const float*)d_in[0];
    const int*   adj     = (const int*)d_in[1];
    const float* W_heads = (const float*)d_in[2];
    const float* a_heads = (const float*)d_in[3];
    const float* bnh_g   = (const float*)d_in[4];
    const float* bnh_b   = (const float*)d_in[5];
    const float* bnt_g   = (const float*)d_in[6];
    const float* bnt_b   = (const float*)d_in[7];
    const float* W_sent  = (const float*)d_in[8];
    const float* a_sent  = (const float*)d_in[9];
    const float* bns_g   = (const float*)d_in[10];
    const float* bns_b   = (const float*)d_in[11];
    const float* W_para  = (const float*)d_in[12];
    const float* a_para  = (const float*)d_in[13];
    const float* bnp_g   = (const float*)d_in[14];
    const float* bnp_b   = (const float*)d_in[15];
    const float* W_q     = (const float*)d_in[16];
    const float* a_q     = (const float*)d_in[17];
    const float* bnq_g   = (const float*)d_in[18];
    const float* bnq_b   = (const float*)d_in[19];
    const float* W2      = (const float*)d_in[20];
    float* out = (float*)d_out;
    float* ws  = (float*)d_ws;

    _Float16* h16   = (_Float16*)ws;              // 6,553,600 h = 3,276,800 f
    _Float16* x16h  = (_Float16*)(ws + 3276800);  // 6,553,600 h (head-major [8][25600][32])
    _Float16* W2t48 = (_Float16*)(ws + 6553600);  // 12,288 h = 6,144 f
    _Float16* Bt    = (_Float16*)(ws + 6559744);  // 196,608 h = 98,304 f
    unsigned int* maskw = (unsigned int*)(ws + 6658048);  // 204,800 words
    float* H2p   = ws + 6862848;                  // 1,228,800 f (end ~32.4 MB)

    prep<<<dim3(1793), dim3(256), 0, stream>>>(adj, W_heads, W_sent, W_para, W_q,
                                               a_sent, a_para, a_q, maskw, Bt, W2t48);
    gemm1_s<<<dim3(800), dim3(256), 0, stream>>>(feat, Bt, h16);
    attn_heads_mfma<<<dim3(1024), dim3(256), 0, stream>>>(h16, a_heads, maskw,
                                                          bnh_g, bnh_b, bnt_g, bnt_b, x16h);
    gemm2m<<<dim3(400), dim3(256), 0, stream>>>(x16h, W2t48, H2p);
    attn_spq<<<dim3(128, 3), dim3(256), 0, stream>>>(H2p, maskw, bns_g, bns_b,
                                                     bnp_g, bnp_b, bnq_g, bnq_b, W2, out);
}

// Round 9
// 280.884 us; speedup vs baseline: 1.4255x; 1.0931x over previous
//
#include <hip/hip_runtime.h>
#include <hip/hip_bf16.h>
#include <cstdint>

#define BN_SCALEF 0.99999500003749975f  // 1/sqrt(1+1e-5)
#define EXP_SHIFT 4.0f

// Problem constants: B=128, N=200, F=768, H=8, Fo=32, Fh=256

typedef _Float16 half8 __attribute__((ext_vector_type(8)));
typedef _Float16 half4 __attribute__((ext_vector_type(4)));
typedef float floatx4 __attribute__((ext_vector_type(4)));

// ---------------------------------------------------------------- prep: pack_mask + Wcat^T + W2t48 (one launch)

__global__ __launch_bounds__(256) void prep(const int* __restrict__ adj,
                                            const float* __restrict__ W_heads,
                                            const float* __restrict__ Ws_in,
                                            const float* __restrict__ Wp_in,
                                            const float* __restrict__ Wq_in,
                                            const float* __restrict__ a_sent,
                                            const float* __restrict__ a_para,
                                            const float* __restrict__ a_q,
                                            unsigned int* __restrict__ maskw,
                                            _Float16* __restrict__ Bt,
                                            _Float16* __restrict__ W2t48) {
    int blk = blockIdx.x;
    int t = threadIdx.x;
    if (blk < 1600) {
        int w = t >> 6, lane = t & 63;
        for (int task = w; task < 64; task += 4) {
            int r = blk * 16 + (task >> 2);
            int c0 = (task & 3) * 64;
            int j = c0 + lane;
            bool v = (j < 200) && (adj[(size_t)r * 200 + j] > 0);
            unsigned long long m = __ballot(v ? 1 : 0);
            if (lane == 0) {
                maskw[r * 8 + (c0 >> 5)]     = (unsigned int)(m & 0xffffffffULL);
                maskw[r * 8 + (c0 >> 5) + 1] = (unsigned int)(m >> 32);
            }
        }
    } else if (blk < 1792) {
        __shared__ float ld[32][36];
        int blk2 = blk - 1600;          // h = blk2/24, f-tile = blk2%24
        int h = blk2 / 24, f0 = (blk2 % 24) * 32;
        int idx = t * 4;
        int fr = idx >> 5, o0 = idx & 31;
        float4 v = *(const float4*)&W_heads[(size_t)h * 24576 + (size_t)(f0 + fr) * 32 + o0];
        ld[fr][o0] = v.x; ld[fr][o0 + 1] = v.y; ld[fr][o0 + 2] = v.z; ld[fr][o0 + 3] = v.w;
        __syncthreads();
        int o = idx >> 5, fr0 = idx & 31;
        half4 hv;
#pragma unroll
        for (int u = 0; u < 4; ++u) hv[u] = (_Float16)ld[fr0 + u][o];
        *(half4*)&Bt[(size_t)(h * 32 + o) * 768 + f0 + fr0] = hv;
    } else {
        int k = t;  // 256
        for (int c = 0; c < 36; ++c) {
            float v;
            if (c < 2)      v = Ws_in[k * 2 + c];
            else if (c < 4) v = Wp_in[k * 2 + (c - 2)];
            else            v = Wq_in[k * 32 + (c - 4)];
            W2t48[c * 256 + k] = (_Float16)v;
        }
        W2t48[36 * 256 + k] = (_Float16)(Ws_in[k * 2] * a_sent[0] + Ws_in[k * 2 + 1] * a_sent[1]);
        W2t48[37 * 256 + k] = (_Float16)(Ws_in[k * 2] * a_sent[2] + Ws_in[k * 2 + 1] * a_sent[3]);
        W2t48[38 * 256 + k] = (_Float16)(Wp_in[k * 2] * a_para[0] + Wp_in[k * 2 + 1] * a_para[1]);
        W2t48[39 * 256 + k] = (_Float16)(Wp_in[k * 2] * a_para[2] + Wp_in[k * 2 + 1] * a_para[3]);
        float q1 = 0.f, q2 = 0.f;
#pragma unroll
        for (int o = 0; o < 32; ++o) {
            q1 += Wq_in[k * 32 + o] * a_q[o];
            q2 += Wq_in[k * 32 + o] * a_q[32 + o];
        }
        W2t48[40 * 256 + k] = (_Float16)q1;
        W2t48[41 * 256 + k] = (_Float16)q2;
        for (int c = 42; c < 48; ++c) W2t48[c * 256 + k] = (_Float16)0.f;
    }
}

// ---------------------------------------------------------------- GEMM1: R4-proven structure
// h16[25600,256] = A[25600,768] fp32 @ Bt^T (f16 [256][768])
// tile 64x256, 512 thr = 8 waves (2x4), wave = 2x4 tiles of 16x16, BK=32, grid 400.

__global__ __launch_bounds__(512) void gemm1_mfma(const float* __restrict__ A,
                                                  const _Float16* __restrict__ Bt,
                                                  _Float16* __restrict__ h16) {
    __shared__ __align__(16) _Float16 As[64 * 40];    // [row][k], pad 8
    __shared__ __align__(16) _Float16 Bs[256 * 40];   // [col][k]
    int t = threadIdx.x;
    int m0 = blockIdx.x * 64;
    int w = t >> 6, lane = t & 63;
    int wr = w >> 2, wc = w & 3;
    int quad = lane >> 4, l16 = lane & 15;

    floatx4 acc[2][4];
#pragma unroll
    for (int i = 0; i < 2; ++i)
#pragma unroll
        for (int j = 0; j < 4; ++j) acc[i][j] = (floatx4){0.f, 0.f, 0.f, 0.f};

    int arow = t >> 3, ako = (t & 7) * 4;      // A: 64 rows x 32 k, one float4/thread
    int bcol = t >> 1, bko = (t & 1) * 16;     // B: 256 cols x 32 k, two uint4/thread
    const float*    Aptr = &A[(size_t)(m0 + arow) * 768 + ako];
    const _Float16* Bptr = &Bt[(size_t)bcol * 768 + bko];

    float4 pa  = *(const float4*)(Aptr);
    uint4  pb0 = *(const uint4*)(Bptr);
    uint4  pb1 = *(const uint4*)(Bptr + 8);

    for (int k0 = 0; k0 < 768; k0 += 32) {
        half4 ah;
        ah[0] = (_Float16)pa.x; ah[1] = (_Float16)pa.y;
        ah[2] = (_Float16)pa.z; ah[3] = (_Float16)pa.w;
        *(half4*)&As[arow * 40 + ako] = ah;
        *(uint4*)&Bs[bcol * 40 + bko]     = pb0;
        *(uint4*)&Bs[bcol * 40 + bko + 8] = pb1;
        __syncthreads();
        if (k0 + 32 < 768) {
            pa  = *(const float4*)(Aptr + k0 + 32);
            pb0 = *(const uint4*)(Bptr + k0 + 32);
            pb1 = *(const uint4*)(Bptr + k0 + 40);
        }
        half8 af[2], bf[4];
#pragma unroll
        for (int rt = 0; rt < 2; ++rt)
            af[rt] = *(half8*)&As[(wr * 32 + rt * 16 + l16) * 40 + quad * 8];
#pragma unroll
        for (int ct = 0; ct < 4; ++ct)
            bf[ct] = *(half8*)&Bs[(wc * 64 + ct * 16 + l16) * 40 + quad * 8];
#pragma unroll
        for (int rt = 0; rt < 2; ++rt)
#pragma unroll
            for (int ct = 0; ct < 4; ++ct)
                acc[rt][ct] = __builtin_amdgcn_mfma_f32_16x16x32_f16(af[rt], bf[ct], acc[rt][ct], 0, 0, 0);
        __syncthreads();
    }

    int rbase = m0 + wr * 32;
    int cbase = wc * 64;
#pragma unroll
    for (int rt = 0; rt < 2; ++rt)
#pragma unroll
        for (int ct = 0; ct < 4; ++ct) {
            int gc = cbase + ct * 16 + l16;
#pragma unroll
            for (int r = 0; r < 4; ++r) {
                int gr = rbase + rt * 16 + quad * 4 + r;
                h16[(size_t)gr * 256 + gc] = (_Float16)acc[rt][ct][r];
            }
        }
}

// ---------------------------------------------------------------- head attention via MFMA (h16 in, x16 head-major out)
// Constant-trip loops, no private arrays (scratch-safe); dist-1 mask prefetch.

__global__ __launch_bounds__(256) void attn_heads_mfma(
    const _Float16* __restrict__ h16,
    const float* __restrict__ a_h,
    const unsigned int* __restrict__ maskw,
    const float* __restrict__ bnh_g, const float* __restrict__ bnh_b,
    const float* __restrict__ bnt_g, const float* __restrict__ bnt_b,
    _Float16* __restrict__ x16h) {
    __shared__ __align__(16) _Float16 Bs[48 * 228];   // [n][k]: n<32 h^T, n=32 ones, rest 0
    __shared__ __align__(16) _Float16 Ps[64 * 228];   // 4 waves x 16-row slabs
    __shared__ float s1s[256], s2s[256];
    int hb = blockIdx.x;
    int h = hb >> 7, b = hb & 127;
    int t = threadIdx.x;

    unsigned long long* bz = (unsigned long long*)Bs;
    for (int idx = t; idx < (48 * 228) / 4; idx += 256) bz[idx] = 0ULL;
    __syncthreads();
    for (int idx = t; idx < 800; idx += 256) {
        int j = idx >> 2, w8 = (idx & 3) * 8;
        half8 v = *(const half8*)&h16[(size_t)(b * 200 + j) * 256 + h * 32 + w8];
#pragma unroll
        for (int u = 0; u < 8; ++u) Bs[(w8 + u) * 228 + j] = v[u];
    }
    if (t < 200) Bs[32 * 228 + t] = (_Float16)1.0f;
    __syncthreads();

    if (t < 200) {
        float acc1 = 0.f, acc2 = 0.f;
        const float* ab = &a_h[h * 64];
#pragma unroll
        for (int o = 0; o < 32; ++o) {
            float hv = (float)Bs[o * 228 + t];
            acc1 += hv * ab[o];
            acc2 += hv * ab[32 + o];
        }
        s1s[t] = acc1; s2s[t] = acc2;
    } else {
        s1s[t] = 0.f; s2s[t] = 0.f;
    }
    __syncthreads();

    int w = t >> 6, lane = t & 63;
    int l16 = lane & 15, quad = lane >> 4;
    _Float16* Pw = &Ps[w * 16 * 228];

    int j0 = lane * 4;
    float4 s2r = *(const float4*)&s2s[j0];
    const unsigned int* mbase = &maskw[(size_t)(b * 200) * 8 + (lane >> 3)];

    for (int tile = w; tile < 13; tile += 4) {
        int i_base = tile * 16;
        // dist-1 prefetch of the per-row mask word (no private array -> no scratch)
        unsigned int mw = mbase[(size_t)i_base * 8];
        for (int r16 = 0; r16 < 16; ++r16) {
            int i = i_base + r16;
            unsigned int mw_next = 0;
            if (r16 < 15) {
                int in = i + 1; in = in < 200 ? in : 199;
                mw_next = mbase[(size_t)in * 8];
            }
            float s1v = s1s[i];          // rows 200..207: s1s=0, outputs masked later
            half4 pv;
#pragma unroll
            for (int q = 0; q < 4; ++q) {
                float e = s1v + ((const float*)&s2r)[q];
                e = fmaxf(e, 0.3f * e);
                float p = ((mw >> ((j0 + q) & 31)) & 1u) ? __expf(e - EXP_SHIFT) : 0.f;
                pv[q] = (_Float16)p;
            }
            if (j0 < 228) *(half4*)&Pw[r16 * 228 + j0] = pv;
            mw = mw_next;
        }
        floatx4 acc0 = {0.f, 0.f, 0.f, 0.f};
        floatx4 acc1 = {0.f, 0.f, 0.f, 0.f};
        floatx4 acc2 = {0.f, 0.f, 0.f, 0.f};
#pragma unroll
        for (int kt = 0; kt < 7; ++kt) {
            half8 af = *(half8*)&Pw[l16 * 228 + kt * 32 + quad * 8];
            half8 b0 = *(half8*)&Bs[(l16) * 228 + kt * 32 + quad * 8];
            half8 b1 = *(half8*)&Bs[(16 + l16) * 228 + kt * 32 + quad * 8];
            half8 b2 = *(half8*)&Bs[(32 + l16) * 228 + kt * 32 + quad * 8];
            acc0 = __builtin_amdgcn_mfma_f32_16x16x32_f16(af, b0, acc0, 0, 0, 0);
            acc1 = __builtin_amdgcn_mfma_f32_16x16x32_f16(af, b1, acc1, 0, 0, 0);
            acc2 = __builtin_amdgcn_mfma_f32_16x16x32_f16(af, b2, acc2, 0, 0, 0);
        }
#pragma unroll
        for (int r = 0; r < 4; ++r) {
            int i = i_base + quad * 4 + r;
            float rsum = __shfl(acc2[r], (lane & 48), 64);
            if (i < 200) {
                float inv = 1.f / rsum;
                float g1 = BN_SCALEF * bnh_g[h * 200 + i], c1 = bnh_b[h * 200 + i];
                float g2 = BN_SCALEF * bnt_g[i], c2 = bnt_b[i];
                float v0 = acc0[r] * inv * g1 + c1;
                v0 = v0 > 0.f ? v0 : __expf(v0) - 1.f;
                v0 = v0 * g2 + c2;
                float v1 = acc1[r] * inv * g1 + c1;
                v1 = v1 > 0.f ? v1 : __expf(v1) - 1.f;
                v1 = v1 * g2 + c2;
                size_t base = (size_t)h * 819200 + (size_t)(b * 200 + i) * 32;
                x16h[base + l16]      = (_Float16)v0;
                x16h[base + 16 + l16] = (_Float16)v1;
            }
        }
    }
}

// ---------------------------------------------------------------- GEMM2 via MFMA: H2p[25600][48] = x16h @ W2t48^T

__global__ __launch_bounds__(256) void gemm2m(const _Float16* __restrict__ Xh,
                                              const _Float16* __restrict__ Wt,
                                              float* __restrict__ H2p) {
    __shared__ __align__(16) _Float16 Xs[64 * 264];   // [row][k = h*32+o], pad 8
    __shared__ __align__(16) _Float16 Ws[48 * 264];
    int t = threadIdx.x;
    int m0 = blockIdx.x * 64;       // 400 blocks
    int srow = t >> 2, schunk = (t & 3) * 8;
#pragma unroll
    for (int h = 0; h < 8; ++h) {
        half8 v = *(const half8*)&Xh[(size_t)h * 819200 + (size_t)(m0 + srow) * 32 + schunk];
        *(half8*)&Xs[srow * 264 + h * 32 + schunk] = v;
    }
#pragma unroll
    for (int p = 0; p < 6; ++p) {
        int g = t + 256 * p;                 // 1536 half8 chunks
        int n = g >> 5, ko = (g & 31) * 8;
        *(half8*)&Ws[n * 264 + ko] = *(const half8*)&Wt[(size_t)n * 256 + ko];
    }
    __syncthreads();

    int w = t >> 6, lane = t & 63;
    int l16 = lane & 15, quad = lane >> 4;
    int rbase = w * 16;
    floatx4 acc[3];
#pragma unroll
    for (int c = 0; c < 3; ++c) acc[c] = (floatx4){0.f, 0.f, 0.f, 0.f};
#pragma unroll
    for (int kt = 0; kt < 8; ++kt) {
        half8 af = *(half8*)&Xs[(rbase + l16) * 264 + kt * 32 + quad * 8];
#pragma unroll
        for (int ct = 0; ct < 3; ++ct) {
            half8 bf = *(half8*)&Ws[(ct * 16 + l16) * 264 + kt * 32 + quad * 8];
            acc[ct] = __builtin_amdgcn_mfma_f32_16x16x32_f16(af, bf, acc[ct], 0, 0, 0);
        }
    }
#pragma unroll
    for (int ct = 0; ct < 3; ++ct) {
        int col = ct * 16 + l16;
#pragma unroll
        for (int r = 0; r < 4; ++r) {
            int row = m0 + rbase + quad * 4 + r;
            H2p[(size_t)row * 48 + col] = acc[ct][r];
        }
    }
}

// ---------------------------------------------------------------- sent+para+q attention
// H2p cols: 0-1 sent h2, 2-3 para h2, 4-35 q h2, 36/37 s1/s2 sent, 38/39 para, 40/41 q

__global__ __launch_bounds__(256) void attn_spq(const float* __restrict__ H2p,
                                                const unsigned int* __restrict__ maskw,
                                                const float* __restrict__ bns_g, const float* __restrict__ bns_b,
                                                const float* __restrict__ bnp_g, const float* __restrict__ bnp_b,
                                                const float* __restrict__ bnq_g, const float* __restrict__ bnq_b,
                                                const float* __restrict__ W2, float* __restrict__ out) {
    int b = blockIdx.x;
    int t = threadIdx.x;
    if (blockIdx.y == 2) {
        __shared__ float p_lds[200];
        __shared__ float redd[4];
        __shared__ float red2[256];
        float s1v = H2p[(size_t)(b * 200) * 48 + 40];
        float p = 0.f;
        if (t < 200) {
            unsigned int mw = maskw[(size_t)(b * 200) * 8 + (t >> 5)];
            if ((mw >> (t & 31)) & 1u) {
                float x = s1v + H2p[(size_t)(b * 200 + t) * 48 + 41];
                x = fmaxf(x, 0.3f * x);
                p = __expf(x - EXP_SHIFT);
            }
            p_lds[t] = p;
        }
        float ds = p;
        for (int off = 32; off; off >>= 1) ds += __shfl_xor(ds, off, 64);
        if ((t & 63) == 0) redd[t >> 6] = ds;
        __syncthreads();
        ds = redd[0] + redd[1] + redd[2] + redd[3];
        int o = t & 31, g = t >> 5;
        float acc = 0.f;
        for (int j = g; j < 200; j += 8)
            acc += p_lds[j] * H2p[(size_t)(b * 200 + j) * 48 + 4 + o];
        red2[t] = acc;
        __syncthreads();
        if (t < 32) {
            float s = 0.f;
#pragma unroll
            for (int gg = 0; gg < 8; ++gg) s += red2[gg * 32 + t];
            float qv = (s / ds) * (BN_SCALEF * bnq_g[0]) + bnq_b[0];
            float c0 = qv * W2[t * 2], c1 = qv * W2[t * 2 + 1];
#pragma unroll
            for (int off = 16; off; off >>= 1) {
                c0 += __shfl_xor(c0, off, 64);
                c1 += __shfl_xor(c1, off, 64);
            }
            if (t == 0) {
                out[102400 + b * 2 + 0] = c0 > 0.f ? c0 : __expf(c0) - 1.f;
                out[102400 + b * 2 + 1] = c1 > 0.f ? c1 : __expf(c1) - 1.f;
            }
        }
        return;
    }
    __shared__ float s2s[200], s2p[200];
    __shared__ float s1sA[200], s1pA[200];
    __shared__ __align__(16) float hsp[200 * 4];
    int chunk = blockIdx.y;
    if (t < 200) {
        const float* hr = &H2p[(size_t)(b * 200 + t) * 48];
        float4 hv = *(const float4*)hr;
        *(float4*)&hsp[t * 4] = hv;
        s1sA[t] = hr[36]; s2s[t] = hr[37];
        s1pA[t] = hr[38]; s2p[t] = hr[39];
    }
    __syncthreads();
    int w = t >> 6, lane = t & 63;
    for (int it = 0; it < 25; ++it) {
        int i = chunk * 100 + it * 4 + w;
        float s1sv = s1sA[i];
        float s1pv = s1pA[i];
        float ds = 0.f, dp = 0.f, pa0 = 0.f, pa1 = 0.f, pb0 = 0.f, pb1 = 0.f;
#pragma unroll
        for (int q = 0; q < 4; ++q) {
            int j = lane + 64 * q;
            if (j < 200) {
                unsigned int mw = maskw[(size_t)(b * 200 + i) * 8 + (j >> 5)];
                if ((mw >> (j & 31)) & 1u) {
                    float x1 = s1sv + s2s[j]; x1 = fmaxf(x1, 0.3f * x1);
                    float x2 = s1pv + s2p[j]; x2 = fmaxf(x2, 0.3f * x2);
                    float p1 = __expf(x1 - EXP_SHIFT), p2 = __expf(x2 - EXP_SHIFT);
                    ds += p1; dp += p2;
                    float4 hv = *(float4*)&hsp[j * 4];
                    pa0 += p1 * hv.x; pa1 += p1 * hv.y;
                    pb0 += p2 * hv.z; pb1 += p2 * hv.w;
                }
            }
        }
        for (int off = 32; off; off >>= 1) {
            ds  += __shfl_xor(ds, off, 64);  dp  += __shfl_xor(dp, off, 64);
            pa0 += __shfl_xor(pa0, off, 64); pa1 += __shfl_xor(pa1, off, 64);
            pb0 += __shfl_xor(pb0, off, 64); pb1 += __shfl_xor(pb1, off, 64);
        }
        if (lane == 0) {
            float gs = BN_SCALEF * bns_g[i], bs = bns_b[i];
            float v0 = (pa0 / ds) * gs + bs, v1 = (pa1 / ds) * gs + bs;
            out[(size_t)(b * 200 + i) * 2 + 0] = 1.f / (1.f + __expf(-v0));
            out[(size_t)(b * 200 + i) * 2 + 1] = 1.f / (1.f + __expf(-v1));
            float gp = BN_SCALEF * bnp_g[i], bp = bnp_b[i];
            float u0 = (pb0 / dp) * gp + bp, u1 = (pb1 / dp) * gp + bp;
            out[51200 + (size_t)(b * 200 + i) * 2 + 0] = u0 > 0.f ? u0 : __expf(u0) - 1.f;
            out[51200 + (size_t)(b * 200 + i) * 2 + 1] = u1 > 0.f ? u1 : __expf(u1) - 1.f;
        }
    }
}

// ---------------------------------------------------------------- launch

extern "C" void kernel_launch(void* const* d_in, const int* in_sizes, int n_in,
                              void* d_out, int out_size, void* d_ws, size_t ws_size,
                              hipStream_t stream) {
    (void)in_sizes; (void)n_in; (void)out_size; (void)ws_size;
    const float* feat    = (const float*)d_in[0];
    const int*   adj     = (const int*)d_in[1];
    const float* W_heads = (const float*)d_in[2];
    const float* a_heads = (const float*)d_in[3];
    const float* bnh_g   = (const float*)d_in[4];
    const float* bnh_b   = (const float*)d_in[5];
    const float* bnt_g   = (const float*)d_in[6];
    const float* bnt_b   = (const float*)d_in[7];
    const float* W_sent  = (const float*)d_in[8];
    const float* a_sent  = (const float*)d_in[9];
    const float* bns_g   = (const float*)d_in[10];
    const float* bns_b   = (const float*)d_in[11];
    const float* W_para  = (const float*)d_in[12];
    const float* a_para  = (const float*)d_in[13];
    const float* bnp_g   = (const float*)d_in[14];
    const float* bnp_b   = (const float*)d_in[15];
    const float* W_q     = (const float*)d_in[16];
    const float* a_q     = (const float*)d_in[17];
    const float* bnq_g   = (const float*)d_in[18];
    const float* bnq_b   = (const float*)d_in[19];
    const float* W2      = (const float*)d_in[20];
    float* out = (float*)d_out;
    float* ws  = (float*)d_ws;

    _Float16* h16   = (_Float16*)ws;              // 6,553,600 h = 3,276,800 f
    _Float16* x16h  = (_Float16*)(ws + 3276800);  // 6,553,600 h (head-major [8][25600][32])
    _Float16* W2t48 = (_Float16*)(ws + 6553600);  // 12,288 h = 6,144 f
    _Float16* Bt    = (_Float16*)(ws + 6559744);  // 196,608 h = 98,304 f
    unsigned int* maskw = (unsigned int*)(ws + 6658048);  // 204,800 words
    float* H2p   = ws + 6862848;                  // 1,228,800 f (end ~32.4 MB)

    prep<<<dim3(1793), dim3(256), 0, stream>>>(adj, W_heads, W_sent, W_para, W_q,
                                               a_sent, a_para, a_q, maskw, Bt, W2t48);
    gemm1_mfma<<<dim3(400), dim3(512), 0, stream>>>(feat, Bt, h16);
    attn_heads_mfma<<<dim3(1024), dim3(256), 0, stream>>>(h16, a_heads, maskw,
                                                          bnh_g, bnh_b, bnt_g, bnt_b, x16h);
    gemm2m<<<dim3(400), dim3(256), 0, stream>>>(x16h, W2t48, H2p);
    attn_spq<<<dim3(128, 3), dim3(256), 0, stream>>>(H2p, maskw, bns_g, bns_b,
                                                     bnp_g, bnp_b, bnq_g, bnq_b, W2, out);
}